// Round 3
// baseline (902.645 us; speedup 1.0000x reference)
//
#include <hip/hip_runtime.h>
#include <hip/hip_bf16.h>
#include <stdint.h>

typedef unsigned short u16;
typedef unsigned int u32;

#define F1 274625   // 65^3
#define IJ1 4225    // 65^2

typedef float v4f __attribute__((ext_vector_type(4)));
typedef __bf16 v8bf __attribute__((ext_vector_type(8)));

__device__ __forceinline__ float lof(u32 u) { union { u32 u; float f; } c; c.u = u << 16; return c.f; }
__device__ __forceinline__ u16 f2bf(float f) {
  union { float f; u32 u; } c; c.f = f;
  u32 r = (c.u >> 16) & 1u;
  return (u16)((c.u + 0x7fffu + r) >> 16);
}
__device__ __forceinline__ u32 pkbf(u32 a, u32 b) {
  union { float f; u32 u; } ca, cb; ca.u = a; cb.u = b;
  __hip_bfloat162 h = __float22bfloat162_rn(make_float2(ca.f, cb.f));
  union { __hip_bfloat162 h; u32 u; } c; c.h = h; return c.u;
}

// ---------------- K1: bilinear -> zsum [3][64][512] f32 (direct store, no memset)
// z_t[b,o] = sum_i x1[b,i] * sum_j zw_t[o,i,j] * vec3[b,j]
__global__ void __launch_bounds__(256) k1_bilinear(
    const float* __restrict__ v1, const float* __restrict__ v2, const float* __restrict__ v3,
    const float* __restrict__ zw1, const float* __restrict__ zw2, const float* __restrict__ zw3,
    float* __restrict__ zsum) {
  int bid = blockIdx.x;                 // 384 = t*128 + o*2 + bh
  int bh = bid & 1, o = (bid >> 1) & 63, t = bid >> 7;
  int b = bh * 256 + threadIdx.x;
  const float* zw = (t == 0) ? zw1 : ((t == 1) ? zw2 : zw3);
  const float* xv = (t == 1) ? v2 : v1;      // branches 0,2 use vec1; 1 uses vec2
  float x3r[64];
  const float4* x34 = (const float4*)(v3 + b * 64);
#pragma unroll
  for (int q = 0; q < 16; ++q) {
    float4 a = x34[q];
    x3r[q*4+0] = a.x; x3r[q*4+1] = a.y; x3r[q*4+2] = a.z; x3r[q*4+3] = a.w;
  }
  const float4* w4 = (const float4*)(zw + o * 4096);
  const float* xrow = xv + b * 64;
  float acc = 0.f;
#pragma unroll 4
  for (int i = 0; i < 64; ++i) {
    float xi = xrow[i];
    float s = 0.f;
#pragma unroll
    for (int q = 0; q < 16; ++q) {
      float4 w = w4[i * 16 + q];   // uniform index -> scalar loads
      s += w.x * x3r[q*4+0] + w.y * x3r[q*4+1] + w.z * x3r[q*4+2] + w.w * x3r[q*4+3];
    }
    acc += xi * s;
  }
  zsum[t * 32768 + o * 512 + b] = acc;
}

// ---------------- K2: per-branch h/o layers -> oT f32 [3][65][512], o3row bf16 [512][72]
__global__ void __launch_bounds__(256) k2_branch(
    const float* __restrict__ v1, const float* __restrict__ v2, const float* __restrict__ v3,
    const float* __restrict__ hw1, const float* __restrict__ hb1,
    const float* __restrict__ ow1, const float* __restrict__ ob1,
    const float* __restrict__ hw2, const float* __restrict__ hb2,
    const float* __restrict__ ow2, const float* __restrict__ ob2,
    const float* __restrict__ hw3, const float* __restrict__ hb3,
    const float* __restrict__ ow3, const float* __restrict__ ob3,
    const float* __restrict__ zb1, const float* __restrict__ zb2, const float* __restrict__ zb3,
    const float* __restrict__ zsum,
    float* __restrict__ oT, u16* __restrict__ o3row) {
  int t = blockIdx.x >> 3, bc = blockIdx.x & 7;   // 24 blocks
  int lane = threadIdx.x & 63;
  int w = __builtin_amdgcn_readfirstlane((int)(threadIdx.x >> 6));
  int b = bc * 64 + lane;
  const float* hw = (t==0)?hw1:((t==1)?hw2:hw3);
  const float* hb = (t==0)?hb1:((t==1)?hb2:hb3);
  const float* ow = (t==0)?ow1:((t==1)?ow2:ow3);
  const float* ob = (t==0)?ob1:((t==1)?ob2:ob3);
  const float* zb = (t==0)?zb1:((t==1)?zb2:zb3);
  const float* xv = (t==0)?v1:((t==1)?v2:v3);
  const float4* hw4 = (const float4*)hw;
  const float4* ow4 = (const float4*)ow;
  __shared__ float gT[64][68];
  float xr[64];
  const float4* xv4 = (const float4*)(xv + b * 64);
#pragma unroll
  for (int q = 0; q < 16; ++q) {
    float4 a = xv4[q];
    xr[q*4+0] = a.x; xr[q*4+1] = a.y; xr[q*4+2] = a.z; xr[q*4+3] = a.w;
  }
#pragma unroll
  for (int ii = 0; ii < 16; ii += 4) {
    float gv[4];
#pragma unroll
    for (int q = 0; q < 4; ++q) {
      int i = w * 16 + ii + q;
      float a = hb[i];
#pragma unroll
      for (int kq = 0; kq < 16; ++kq) {
        float4 h4 = hw4[i * 16 + kq];
        a += h4.x * xr[kq*4+0] + h4.y * xr[kq*4+1] + h4.z * xr[kq*4+2] + h4.w * xr[kq*4+3];
      }
      float hv = fmaxf(a, 0.f);
      float z = zsum[t * 32768 + i * 512 + b] + zb[i];
      float sg = 1.f / (1.f + __expf(-z));
      gv[q] = sg * hv;
    }
    *(float4*)&gT[lane][w * 16 + ii] = make_float4(gv[0], gv[1], gv[2], gv[3]);
  }
  __syncthreads();
  float gr[64];
#pragma unroll
  for (int k = 0; k < 64; k += 4) {
    float4 g4 = *(const float4*)&gT[lane][k];
    gr[k] = g4.x; gr[k+1] = g4.y; gr[k+2] = g4.z; gr[k+3] = g4.w;
  }
#pragma unroll
  for (int ii = 0; ii < 16; ++ii) {
    int oo = w * 16 + ii;
    float a = ob[oo];
#pragma unroll
    for (int kq = 0; kq < 16; ++kq) {
      float4 o4 = ow4[oo * 16 + kq];
      a += o4.x * gr[kq*4+0] + o4.y * gr[kq*4+1] + o4.z * gr[kq*4+2] + o4.w * gr[kq*4+3];
    }
    float ov = fmaxf(a, 0.f);
    oT[(t * 65 + oo) * 512 + b] = ov;
    if (t == 2) o3row[b * 72 + oo] = f2bf(ov);
  }
  if (w == 0) oT[(t * 65 + 64) * 512 + b] = 1.f;       // ones column
  if (t == 2 && w == 1) {
    uint4 ones = make_uint4(0x3F80u, 0u, 0u, 0u);      // bf16 1.0, then zero pad
    *(uint4*)&o3row[b * 72 + 64] = ones;
  }
}

// pack one staged W row-half: 32 dwords (+col64 on hh=1), compile-time shift S4
// (pure register renaming). bp = row base in u16 units, plain layout (stride 72).
template<int S4>
__device__ __forceinline__ void pack_row(const uint4* qv, u16* bp, int hh) {
  u32 l[36];
#pragma unroll
  for (int r = 0; r < 9; ++r) {
    l[4*r+0] = qv[r].x; l[4*r+1] = qv[r].y; l[4*r+2] = qv[r].z; l[4*r+3] = qv[r].w;
  }
#pragma unroll
  for (int m = 0; m < 4; ++m) {
    u32 p0 = pkbf(l[S4+8*m+0], l[S4+8*m+1]);
    u32 p1 = pkbf(l[S4+8*m+2], l[S4+8*m+3]);
    u32 p2 = pkbf(l[S4+8*m+4], l[S4+8*m+5]);
    u32 p3 = pkbf(l[S4+8*m+6], l[S4+8*m+7]);
    *(uint4*)(bp + hh * 32 + m * 8) = make_uint4(p0, p1, p2, p3);
  }
  if (hh) bp[64] = (u16)(pkbf(l[S4+32], l[S4+32]) & 0xffffu);  // col 64
}

// ---------------- K4: main GEMM: C[b,o] = sum_f o123[b,f]*W1[o,f]
// 64x128 tile, 1024 blocks (3/CU), double-buffered Bs, ONE raw barrier per ij
// (lgkmcnt only -> global prefetch stays in flight across the barrier).
__global__ void __launch_bounds__(256, 3) k4_gemm(
    const float* __restrict__ W, const u16* __restrict__ o3row,
    const float* __restrict__ oT, float* __restrict__ accum,
    float* __restrict__ pbuf, int mode) {
  __shared__ u16 o3r[64 * 72];
  __shared__ u16 Bs[2][128 * 72];
  __shared__ float o12sf[2][64];
  int bid = blockIdx.x;                 // 1024; 8 mb-sharers of a W slice on same XCD
  int xcd = bid & 7, slot = bid >> 3;   // slot 0..127
  int mb = slot & 7, ph = slot >> 3;    // ph 0..15
  int pair = ph * 8 + xcd;              // 0..127
  int sK = pair >> 1, nb = pair & 1;
  int mbase = mb * 64, nbase = nb * 128;
  int ij0 = (sK * IJ1) >> 6, ij1 = ((sK + 1) * IJ1) >> 6;
  int tid = threadIdx.x;
  {  // persistent o3 rows [64][72] bf16
    const uint4* src = (const uint4*)(o3row + mbase * 72);
    uint4* dst = (uint4*)o3r;
    for (int u = tid; u < 576; u += 256) dst[u] = src[u];
  }
  int lane = tid & 63;
  int wid = __builtin_amdgcn_readfirstlane(tid >> 6);
  int lrow = lane & 15, lkg = lane >> 4;
  int rpos = lane >> 1, hh = lane & 1;   // 32 row-slots per wave, 2 threads/row

  v4f acc[8] = {};
  const uint4* Wq = (const uint4*)W;
  uint4 qv[9];
  float cA = 0.f, cB = 0.f;

  auto loadW = [&](int ij) {
    int cc = (wid - ij) & 3;             // row rotation -> wave-uniform align phase
    int row = rpos * 4 + cc;
    long g = (long)(nbase + row) * F1 + (long)ij * 65;
    long u4 = (g >> 2) + (long)hh * 8;
#pragma unroll
    for (int r = 0; r < 9; ++r) qv[r] = Wq[u4 + r];
  };
  auto loadO = [&](int ij) {
    if (tid < 64) {
      int i = ij / 65, j = ij - i * 65;
      cA = oT[i * 512 + mbase + tid];
      cB = oT[(65 + j) * 512 + mbase + tid];
    }
  };
  auto packCur = [&](int ij, int buf) {
    int cc = (wid - ij) & 3;
    int row = rpos * 4 + cc;
    u16* bp = &Bs[buf][row * 72];
    if      (wid == 0) pack_row<0>(qv, bp, hh);
    else if (wid == 1) pack_row<1>(qv, bp, hh);
    else if (wid == 2) pack_row<2>(qv, bp, hh);
    else               pack_row<3>(qv, bp, hh);
    if (tid < 64) o12sf[buf][tid] = cA * cB;
  };

  loadW(ij0); loadO(ij0);
  __syncthreads();                       // o3r ready
  packCur(ij0, 0);
  loadW(ij0 + 1); loadO(ij0 + 1);
  asm volatile("s_waitcnt lgkmcnt(0)\n\ts_barrier" ::: "memory");

#pragma unroll 1
  for (int ij = ij0; ij < ij1; ++ij) {
    int cur = (ij - ij0) & 1;
    if (ij + 1 < ij1) {
      packCur(ij + 1, cur ^ 1);          // uses qv/cA/cB of ij+1
      if (ij + 2 < ij1) { loadW(ij + 2); loadO(ij + 2); }  // in flight across barrier
    }
    // compute on buffer cur
    const u16* bs = Bs[cur];
    v8bf bf00 = *(const v8bf*)&bs[(wid * 32 +  0 + lrow) * 72 + lkg * 8];
    v8bf bf01 = *(const v8bf*)&bs[(wid * 32 +  0 + lrow) * 72 + lkg * 8 + 32];
    v8bf bf10 = *(const v8bf*)&bs[(wid * 32 + 16 + lrow) * 72 + lkg * 8];
    v8bf bf11 = *(const v8bf*)&bs[(wid * 32 + 16 + lrow) * 72 + lkg * 8 + 32];
    float vv0 = lof((u32)bs[(wid * 32 +  0 + lrow) * 72 + 64]);
    float vv1 = lof((u32)bs[(wid * 32 + 16 + lrow) * 72 + 64]);
    __builtin_amdgcn_s_setprio(1);
#pragma unroll
    for (int t2 = 0; t2 < 4; ++t2) {
      v8bf a0 = *(const v8bf*)&o3r[(t2 * 16 + lrow) * 72 + lkg * 8];
      v8bf a1 = *(const v8bf*)&o3r[(t2 * 16 + lrow) * 72 + lkg * 8 + 32];
      v4f P0 = {}, P1 = {};
      P0 = __builtin_amdgcn_mfma_f32_16x16x32_bf16(a0, bf00, P0, 0, 0, 0);
      P0 = __builtin_amdgcn_mfma_f32_16x16x32_bf16(a1, bf01, P0, 0, 0, 0);
      P1 = __builtin_amdgcn_mfma_f32_16x16x32_bf16(a0, bf10, P1, 0, 0, 0);
      P1 = __builtin_amdgcn_mfma_f32_16x16x32_bf16(a1, bf11, P1, 0, 0, 0);
      float4 sp = *(const float4*)&o12sf[cur][t2 * 16 + lkg * 4];
#pragma unroll
      for (int e = 0; e < 4; ++e) {
        float se = (e == 0) ? sp.x : (e == 1) ? sp.y : (e == 2) ? sp.z : sp.w;
        acc[t2 * 2 + 0][e] += se * (P0[e] + vv0);
        acc[t2 * 2 + 1][e] += se * (P1[e] + vv1);
      }
    }
    __builtin_amdgcn_s_setprio(0);
    asm volatile("s_waitcnt lgkmcnt(0)\n\ts_barrier" ::: "memory");
  }

  if (mode) {
    float* dst = pbuf + ((long)sK << 17);
#pragma unroll
    for (int t2 = 0; t2 < 4; ++t2) {
      int gb0 = mbase + t2 * 16 + lkg * 4;
#pragma unroll
      for (int u2 = 0; u2 < 2; ++u2) {
        int go = nbase + wid * 32 + u2 * 16 + lrow;
#pragma unroll
        for (int e = 0; e < 4; ++e)
          dst[(gb0 + e) * 256 + go] = acc[t2 * 2 + u2][e];
      }
    }
  } else {
#pragma unroll
    for (int t2 = 0; t2 < 4; ++t2) {
      int gb0 = mbase + t2 * 16 + lkg * 4;
#pragma unroll
      for (int u2 = 0; u2 < 2; ++u2) {
        int go = nbase + wid * 32 + u2 * 16 + lrow;
#pragma unroll
        for (int e = 0; e < 4; ++e)
          atomicAdd(&accum[(gb0 + e) * 256 + go], acc[t2 * 2 + u2][e]);
      }
    }
  }
}

// ---------------- K4R: reduce split-K partials, add enc1 bias, relu, TRANSPOSE
// pbuf [64][512][256] -> xrT [256][512]  (written into the accum slot; mode=1 only)
__global__ void __launch_bounds__(256) k4_reduce(const float* __restrict__ P,
    const float* __restrict__ e1b, float* __restrict__ xrT) {
  int g = blockIdx.x * 256 + threadIdx.x;       // float4 index, 32768 total
  const v4f* p4 = (const v4f*)P;
  v4f s = p4[g];
#pragma unroll 4
  for (int k = 1; k < 64; ++k) s += p4[(k << 15) + g];
  int b = g >> 6, c0 = (g & 63) << 2;
#pragma unroll
  for (int e = 0; e < 4; ++e)
    xrT[(c0 + e) * 512 + b] = fmaxf(s[e] + e1b[c0 + e], 0.f);
}

// ---------------- K5: enc2 with relu(enc1)+skip concat -> out f32 [512][256]
// mode=1: xin is xrT [256][512], already biased+relu'd (coalesced reads)
// mode=0: xin is accum [512][256] raw sums (apply bias+relu here)
__global__ void __launch_bounds__(256) k5_enc2(
    const float* __restrict__ xin, const float* __restrict__ oT,
    const float* __restrict__ enc1b, const float* __restrict__ w2,
    const float* __restrict__ enc2b, float* __restrict__ outp, int mode) {
  int bg = blockIdx.x >> 3, og = blockIdx.x & 7;   // 64 blocks
  int lane = threadIdx.x & 63;
  int w = __builtin_amdgcn_readfirstlane((int)(threadIdx.x >> 6));
  int b = bg * 64 + lane;
  int obase = og * 32 + w * 8;
  float a8[8];
#pragma unroll
  for (int q = 0; q < 8; ++q) a8[q] = enc2b[obase + q];
  if (mode) {
    for (int c = 0; c < 256; ++c) {
      float x = xin[c * 512 + b];
#pragma unroll
      for (int q = 0; q < 8; ++q) a8[q] += w2[(obase + q) * 451 + c] * x;
    }
  } else {
    for (int c = 0; c < 256; ++c) {
      float x = fmaxf(xin[b * 256 + c] + enc1b[c], 0.f);
#pragma unroll
      for (int q = 0; q < 8; ++q) a8[q] += w2[(obase + q) * 451 + c] * x;
    }
  }
  for (int e = 0; e < 195; ++e) {
    float x = oT[e * 512 + b];   // rows: o1(65), o2(65), o3(65) — matches concat order
#pragma unroll
    for (int q = 0; q < 8; ++q) a8[q] += w2[(obase + q) * 451 + 256 + e] * x;
  }
#pragma unroll
  for (int q = 0; q < 8; ++q) outp[b * 256 + obase + q] = fmaxf(a8[q], 0.f);
}

extern "C" void kernel_launch(void* const* d_in, const int* in_sizes, int n_in,
                              void* d_out, int out_size, void* d_ws, size_t ws_size,
                              hipStream_t stream) {
  const float* vec1 = (const float*)d_in[0];
  const float* vec2 = (const float*)d_in[1];
  const float* vec3 = (const float*)d_in[2];
  const float* h1w = (const float*)d_in[3];  const float* h1b = (const float*)d_in[4];
  const float* z1w = (const float*)d_in[5];  const float* z1b = (const float*)d_in[6];
  const float* o1w = (const float*)d_in[7];  const float* o1b = (const float*)d_in[8];
  const float* h2w = (const float*)d_in[9];  const float* h2b = (const float*)d_in[10];
  const float* z2w = (const float*)d_in[11]; const float* z2b = (const float*)d_in[12];
  const float* o2w = (const float*)d_in[13]; const float* o2b = (const float*)d_in[14];
  const float* h3w = (const float*)d_in[15]; const float* h3b = (const float*)d_in[16];
  const float* z3w = (const float*)d_in[17]; const float* z3b = (const float*)d_in[18];
  const float* o3w = (const float*)d_in[19]; const float* o3b = (const float*)d_in[20];
  const float* e1w = (const float*)d_in[21]; const float* e1b = (const float*)d_in[22];
  const float* e2w = (const float*)d_in[23]; const float* e2b = (const float*)d_in[24];

  char* ws = (char*)d_ws;
  float* accum = (float*)(ws + 0);              // 512*256*4 = 524288 (mode1: xrT)
  float* oT    = (float*)(ws + 524288);         // 3*65*512*4 = 399360
  u16* o3row   = (u16*)  (ws + 923648);         // 512*72*2   = 73728
  float* zsum  = (float*)(ws + 997376);         // 3*64*512*4 = 393216
  float* pbuf  = (float*)(ws + 1390592);        // 64*512*256*4 = 33554432
  size_t need = 1390592 + (size_t)64 * 512 * 256 * 4;   // 34945024
  int mode = (ws_size >= need) ? 1 : 0;
  float* pArg = mode ? pbuf : accum;

  if (!mode) hipMemsetAsync(accum, 0, 524288, stream);

  hipLaunchKernelGGL(k1_bilinear, dim3(384), dim3(256), 0, stream,
                     vec1, vec2, vec3, z1w, z2w, z3w, zsum);
  hipLaunchKernelGGL(k2_branch, dim3(24), dim3(256), 0, stream,
                     vec1, vec2, vec3,
                     h1w, h1b, o1w, o1b, h2w, h2b, o2w, o2b, h3w, h3b, o3w, o3b,
                     z1b, z2b, z3b, zsum, oT, o3row);
  hipLaunchKernelGGL(k4_gemm, dim3(1024), dim3(256), 0, stream, e1w, o3row, oT, accum,
                     pArg, mode);
  if (mode)
    hipLaunchKernelGGL(k4_reduce, dim3(128), dim3(256), 0, stream, pbuf, e1b, accum);
  hipLaunchKernelGGL(k5_enc2, dim3(64), dim3(256), 0, stream, accum, oT, e1b, e2w, e2b,
                     (float*)d_out, mode);
}

// Round 4
// 750.218 us; speedup vs baseline: 1.2032x; 1.2032x over previous
//
#include <hip/hip_runtime.h>
#include <hip/hip_bf16.h>
#include <stdint.h>

typedef unsigned short u16;
typedef unsigned int u32;

#define F1 274625   // 65^3
#define IJ1 4225    // 65^2

typedef float v4f __attribute__((ext_vector_type(4)));
typedef __bf16 v8bf __attribute__((ext_vector_type(8)));

__device__ __forceinline__ float lof(u32 u) { union { u32 u; float f; } c; c.u = u << 16; return c.f; }
__device__ __forceinline__ u16 f2bf(float f) {
  union { float f; u32 u; } c; c.f = f;
  u32 r = (c.u >> 16) & 1u;
  return (u16)((c.u + 0x7fffu + r) >> 16);
}
__device__ __forceinline__ u32 pkbf(u32 a, u32 b) {
  union { float f; u32 u; } ca, cb; ca.u = a; cb.u = b;
  __hip_bfloat162 h = __float22bfloat162_rn(make_float2(ca.f, cb.f));
  union { __hip_bfloat162 h; u32 u; } c; c.h = h; return c.u;
}

// ---------------- K0: transpose vec1/2/3 [512][64] f32 -> xT [3][64][512] f32
__global__ void __launch_bounds__(256) k0_transpose(const float* __restrict__ v1,
    const float* __restrict__ v2, const float* __restrict__ v3, float* __restrict__ xT) {
  int g = blockIdx.x * 256 + threadIdx.x;
  if (g >= 3 * 64 * 512) return;
  int t = g >> 15, r = g & 32767;
  int d = r >> 9, b = r & 511;
  const float* v = (t == 0) ? v1 : ((t == 1) ? v2 : v3);
  xT[g] = v[b * 64 + d];
}

// ---------------- K1: bilinear -> zsum [3][64][512] f32 (direct store, no memset)
// z_t[b,o] = sum_i x1[b,i] * sum_j zw_t[o,i,j] * vec3[b,j]
__global__ void __launch_bounds__(256) k1_bilinear(
    const float* __restrict__ zw1, const float* __restrict__ zw2, const float* __restrict__ zw3,
    const float* __restrict__ xT, float* __restrict__ zsum) {
  int bid = blockIdx.x;                 // 384 = t*128 + o*2 + bh
  int bh = bid & 1, o = (bid >> 1) & 63, t = bid >> 7;
  int b = bh * 256 + threadIdx.x;
  const float* zw = (t == 0) ? zw1 : ((t == 1) ? zw2 : zw3);
  const float* xiT = xT + ((t == 1) ? 32768 : 0);  // branches 0,2 use vec1; 1 uses vec2
  const float* x3T = xT + 65536;                   // j-side is always vec3
  float x3r[64];
#pragma unroll
  for (int j = 0; j < 64; ++j) x3r[j] = x3T[j * 512 + b];   // coalesced
  const float4* w4 = (const float4*)(zw + o * 4096);
  float acc = 0.f;
#pragma unroll 4
  for (int i = 0; i < 64; ++i) {
    float xi = xiT[i * 512 + b];                             // coalesced
    float s = 0.f;
#pragma unroll
    for (int q = 0; q < 16; ++q) {
      float4 w = w4[i * 16 + q];   // uniform index -> scalar loads
      s += w.x * x3r[q*4+0] + w.y * x3r[q*4+1] + w.z * x3r[q*4+2] + w.w * x3r[q*4+3];
    }
    acc += xi * s;
  }
  zsum[t * 32768 + o * 512 + b] = acc;
}

// ---------------- K2: per-branch h/o layers -> oT f32 [3][65][512], o3row bf16 [512][72]
__global__ void __launch_bounds__(256) k2_branch(
    const float* __restrict__ hw1, const float* __restrict__ hb1,
    const float* __restrict__ ow1, const float* __restrict__ ob1,
    const float* __restrict__ hw2, const float* __restrict__ hb2,
    const float* __restrict__ ow2, const float* __restrict__ ob2,
    const float* __restrict__ hw3, const float* __restrict__ hb3,
    const float* __restrict__ ow3, const float* __restrict__ ob3,
    const float* __restrict__ zb1, const float* __restrict__ zb2, const float* __restrict__ zb3,
    const float* __restrict__ xT, const float* __restrict__ zsum,
    float* __restrict__ oT, u16* __restrict__ o3row) {
  int t = blockIdx.x >> 3, bc = blockIdx.x & 7;   // 24 blocks
  int lane = threadIdx.x & 63;
  int w = __builtin_amdgcn_readfirstlane((int)(threadIdx.x >> 6));
  int b = bc * 64 + lane;
  const float* hw = (t==0)?hw1:((t==1)?hw2:hw3);
  const float* hb = (t==0)?hb1:((t==1)?hb2:hb3);
  const float* ow = (t==0)?ow1:((t==1)?ow2:ow3);
  const float* ob = (t==0)?ob1:((t==1)?ob2:ob3);
  const float* zb = (t==0)?zb1:((t==1)?zb2:zb3);
  const float* xtT = xT + t * 32768;
  const float4* hw4 = (const float4*)hw;
  const float4* ow4 = (const float4*)ow;
  __shared__ float gT[64][68];
  float xr[64];
#pragma unroll
  for (int k = 0; k < 64; ++k) xr[k] = xtT[k * 512 + b];     // coalesced
#pragma unroll
  for (int ii = 0; ii < 16; ii += 4) {
    float gv[4];
#pragma unroll
    for (int q = 0; q < 4; ++q) {
      int i = w * 16 + ii + q;
      float a = hb[i];
#pragma unroll
      for (int kq = 0; kq < 16; ++kq) {
        float4 h4 = hw4[i * 16 + kq];
        a += h4.x * xr[kq*4+0] + h4.y * xr[kq*4+1] + h4.z * xr[kq*4+2] + h4.w * xr[kq*4+3];
      }
      float hv = fmaxf(a, 0.f);
      float z = zsum[t * 32768 + i * 512 + b] + zb[i];
      float sg = 1.f / (1.f + __expf(-z));
      gv[q] = sg * hv;
    }
    *(float4*)&gT[lane][w * 16 + ii] = make_float4(gv[0], gv[1], gv[2], gv[3]);
  }
  __syncthreads();
  float gr[64];
#pragma unroll
  for (int k = 0; k < 64; k += 4) {
    float4 g4 = *(const float4*)&gT[lane][k];
    gr[k] = g4.x; gr[k+1] = g4.y; gr[k+2] = g4.z; gr[k+3] = g4.w;
  }
#pragma unroll
  for (int ii = 0; ii < 16; ++ii) {
    int oo = w * 16 + ii;
    float a = ob[oo];
#pragma unroll
    for (int kq = 0; kq < 16; ++kq) {
      float4 o4 = ow4[oo * 16 + kq];
      a += o4.x * gr[kq*4+0] + o4.y * gr[kq*4+1] + o4.z * gr[kq*4+2] + o4.w * gr[kq*4+3];
    }
    float ov = fmaxf(a, 0.f);
    oT[(t * 65 + oo) * 512 + b] = ov;
    if (t == 2) o3row[b * 72 + oo] = f2bf(ov);
  }
  if (w == 0) oT[(t * 65 + 64) * 512 + b] = 1.f;       // ones column
  if (t == 2 && w == 1) {
    uint4 ones = make_uint4(0x3F80u, 0u, 0u, 0u);      // bf16 1.0, then zero pad
    *(uint4*)&o3row[b * 72 + 64] = ones;
  }
}

// pack one staged W row-half: 32 dwords (+col64 on hh=1), compile-time shift S4
// (pure register renaming). Rotated chunk placement: logical chunk cl stored at
// slot (cl+rpos)&3 within the 64B half -> staging stores span 8 distinct banks.
template<int S4>
__device__ __forceinline__ void pack_row(const uint4* qv, char* half_base,
                                         char* row_base, int rpos, int hh) {
  u32 l[36];
#pragma unroll
  for (int r = 0; r < 9; ++r) {
    l[4*r+0] = qv[r].x; l[4*r+1] = qv[r].y; l[4*r+2] = qv[r].z; l[4*r+3] = qv[r].w;
  }
#pragma unroll
  for (int cl = 0; cl < 4; ++cl) {
    u32 p0 = pkbf(l[S4+8*cl+0], l[S4+8*cl+1]);
    u32 p1 = pkbf(l[S4+8*cl+2], l[S4+8*cl+3]);
    u32 p2 = pkbf(l[S4+8*cl+4], l[S4+8*cl+5]);
    u32 p3 = pkbf(l[S4+8*cl+6], l[S4+8*cl+7]);
    *(uint4*)(half_base + (((cl + rpos) & 3) * 16)) = make_uint4(p0, p1, p2, p3);
  }
  if (hh) *(u16*)(row_base + 128) = (u16)(pkbf(l[S4+32], l[S4+32]) & 0xffffu);  // col 64
}

// ---------------- K4: main GEMM: C[b,o] = sum_f o123[b,f]*W1[o,f]
// 128x128 tile, 512 blocks (2/CU), double-buffered Bs, ONE lgkmcnt barrier per ij
// (global prefetch stays in flight across the barrier), rotated-chunk LDS layout.
__global__ void __launch_bounds__(256, 2) k4_gemm(
    const float* __restrict__ W, const u16* __restrict__ o3row,
    const float* __restrict__ oT, float* __restrict__ accum,
    float* __restrict__ pbuf, int mode) {
  __shared__ u16 o3r[128 * 72];        // rotated layout, 18 KB
  __shared__ u16 Bs[2][128 * 72];      // rotated layout, 2x18 KB
  __shared__ float o12sf[2][128];
  int bid = blockIdx.x;                // 512; 4 mb-sharers of a W slice on same XCD
  int xcd = bid & 7, slot = bid >> 3;
  int mb = slot & 3, ph = slot >> 2;   // ph 0..15
  int pair = ph * 8 + xcd;             // 0..127
  int sK = pair >> 1, nb = pair & 1;   // 64 split-K segments
  int mbase = mb * 128, nbase = nb * 128;
  int ij0 = (sK * IJ1) >> 6, ij1 = ((sK + 1) * IJ1) >> 6;
  int tid = threadIdx.x;
  int lane = tid & 63;
  int wid = __builtin_amdgcn_readfirstlane(tid >> 6);
  int wm = wid >> 1, wn = wid & 1;
  int lrow = lane & 15, lkg = lane >> 4;
  int rpos = lane >> 1, hh = lane & 1;   // 32 row-slots per wave, 2 threads/row

  v4f acc[16] = {};
  const uint4* Wq = (const uint4*)W;
  uint4 qv[9];
  float cA = 0.f, cB = 0.f;

  auto loadW = [&](int ij) {
    int cc = (wid - ij) & 3;             // row rotation -> wave-uniform align phase
    int row = rpos * 4 + cc;
    long g = (long)(nbase + row) * F1 + (long)ij * 65;
    long u4 = (g >> 2) + (long)hh * 8;
#pragma unroll
    for (int r = 0; r < 9; ++r) qv[r] = Wq[u4 + r];
  };
  auto loadO = [&](int ij) {
    if (tid < 128) {
      int i = ij / 65, j = ij - i * 65;
      cA = oT[i * 512 + mbase + tid];
      cB = oT[(65 + j) * 512 + mbase + tid];
    }
  };
  auto packCur = [&](int ij, int buf) {
    int cc = (wid - ij) & 3;
    int row = rpos * 4 + cc;
    char* rb = (char*)Bs[buf] + row * 144;
    char* hb = rb + hh * 64;
    if      (wid == 0) pack_row<0>(qv, hb, rb, rpos, hh);
    else if (wid == 1) pack_row<1>(qv, hb, rb, rpos, hh);
    else if (wid == 2) pack_row<2>(qv, hb, rb, rpos, hh);
    else               pack_row<3>(qv, hb, rb, rpos, hh);
    if (tid < 128) o12sf[buf][tid] = cA * cB;
  };

  loadW(ij0); loadO(ij0);

  // persistent o3 rows [128][cols 0..63] -> rotated layout
  for (int u = tid; u < 1024; u += 256) {
    int r = u >> 3, c = u & 7;
    uint4 v = *(const uint4*)(o3row + (mbase + r) * 72 + c * 8);
    int half = c >> 2, cl = c & 3;
    int slotc = (cl + (r >> 2)) & 3;
    *(uint4*)((char*)o3r + r * 144 + half * 64 + slotc * 16) = v;
  }

  // fragment byte-offsets (rot is t2/u2-independent)
  int rot = ((lkg + (lrow >> 2)) & 3) * 16;
  int aoff[4][2], boff[4][2], vvq[4];
#pragma unroll
  for (int u = 0; u < 4; ++u) {
    int ra = wm * 64 + u * 16 + lrow;
    int rb = wn * 64 + u * 16 + lrow;
#pragma unroll
    for (int k2 = 0; k2 < 2; ++k2) {
      aoff[u][k2] = ra * 144 + k2 * 64 + rot;
      boff[u][k2] = rb * 144 + k2 * 64 + rot;
    }
    vvq[u] = rb * 72 + 64;
  }

  __syncthreads();                       // o3r ready
  packCur(ij0, 0);
  loadW(ij0 + 1); loadO(ij0 + 1);
  asm volatile("s_waitcnt lgkmcnt(0)\n\ts_barrier" ::: "memory");

#pragma unroll 1
  for (int ij = ij0; ij < ij1; ++ij) {
    int cur = (ij - ij0) & 1;
    if (ij + 1 < ij1) {
      packCur(ij + 1, cur ^ 1);          // consumes qv/cA/cB of ij+1
      if (ij + 2 < ij1) { loadW(ij + 2); loadO(ij + 2); }  // in flight across barrier
    }
    const char* bsC = (const char*)Bs[cur];
    v8bf bfr[4][2];
#pragma unroll
    for (int u2 = 0; u2 < 4; ++u2)
#pragma unroll
      for (int k2 = 0; k2 < 2; ++k2)
        bfr[u2][k2] = *(const v8bf*)(bsC + boff[u2][k2]);
    float vv[4];
#pragma unroll
    for (int u2 = 0; u2 < 4; ++u2) vv[u2] = lof((u32)Bs[cur][vvq[u2]]);
    __builtin_amdgcn_s_setprio(1);
#pragma unroll
    for (int t2 = 0; t2 < 4; ++t2) {
      v8bf a0 = *(const v8bf*)((const char*)o3r + aoff[t2][0]);
      v8bf a1 = *(const v8bf*)((const char*)o3r + aoff[t2][1]);
      v4f P0 = {}, P1 = {}, P2 = {}, P3 = {};
      P0 = __builtin_amdgcn_mfma_f32_16x16x32_bf16(a0, bfr[0][0], P0, 0, 0, 0);
      P0 = __builtin_amdgcn_mfma_f32_16x16x32_bf16(a1, bfr[0][1], P0, 0, 0, 0);
      P1 = __builtin_amdgcn_mfma_f32_16x16x32_bf16(a0, bfr[1][0], P1, 0, 0, 0);
      P1 = __builtin_amdgcn_mfma_f32_16x16x32_bf16(a1, bfr[1][1], P1, 0, 0, 0);
      P2 = __builtin_amdgcn_mfma_f32_16x16x32_bf16(a0, bfr[2][0], P2, 0, 0, 0);
      P2 = __builtin_amdgcn_mfma_f32_16x16x32_bf16(a1, bfr[2][1], P2, 0, 0, 0);
      P3 = __builtin_amdgcn_mfma_f32_16x16x32_bf16(a0, bfr[3][0], P3, 0, 0, 0);
      P3 = __builtin_amdgcn_mfma_f32_16x16x32_bf16(a1, bfr[3][1], P3, 0, 0, 0);
      float4 sp = *(const float4*)&o12sf[cur][wm * 64 + t2 * 16 + lkg * 4];
#pragma unroll
      for (int e = 0; e < 4; ++e) {
        float se = (e == 0) ? sp.x : (e == 1) ? sp.y : (e == 2) ? sp.z : sp.w;
        acc[t2 * 4 + 0][e] += se * (P0[e] + vv[0]);
        acc[t2 * 4 + 1][e] += se * (P1[e] + vv[1]);
        acc[t2 * 4 + 2][e] += se * (P2[e] + vv[2]);
        acc[t2 * 4 + 3][e] += se * (P3[e] + vv[3]);
      }
    }
    __builtin_amdgcn_s_setprio(0);
    asm volatile("s_waitcnt lgkmcnt(0)\n\ts_barrier" ::: "memory");
  }

  if (mode) {
    float* dst = pbuf + ((long)sK << 17);
#pragma unroll
    for (int t2 = 0; t2 < 4; ++t2) {
      int gb0 = mbase + wm * 64 + t2 * 16 + lkg * 4;
#pragma unroll
      for (int u2 = 0; u2 < 4; ++u2) {
        int go = nbase + wn * 64 + u2 * 16 + lrow;
#pragma unroll
        for (int e = 0; e < 4; ++e)
          dst[(gb0 + e) * 256 + go] = acc[t2 * 4 + u2][e];
      }
    }
  } else {
#pragma unroll
    for (int t2 = 0; t2 < 4; ++t2) {
      int gb0 = mbase + wm * 64 + t2 * 16 + lkg * 4;
#pragma unroll
      for (int u2 = 0; u2 < 4; ++u2) {
        int go = nbase + wn * 64 + u2 * 16 + lrow;
#pragma unroll
        for (int e = 0; e < 4; ++e)
          atomicAdd(&accum[(gb0 + e) * 256 + go], acc[t2 * 4 + u2][e]);
      }
    }
  }
}

// ---------------- K4R: reduce split-K partials, add enc1 bias, relu, TRANSPOSE
// pbuf [64][512][256] -> xrT [256][512]  (written into the accum slot; mode=1 only)
__global__ void __launch_bounds__(256) k4_reduce(const float* __restrict__ P,
    const float* __restrict__ e1b, float* __restrict__ xrT) {
  int g = blockIdx.x * 256 + threadIdx.x;       // float4 index, 32768 total
  const v4f* p4 = (const v4f*)P;
  v4f s = p4[g];
#pragma unroll 4
  for (int k = 1; k < 64; ++k) s += p4[(k << 15) + g];
  int b = g >> 6, c0 = (g & 63) << 2;
#pragma unroll
  for (int e = 0; e < 4; ++e)
    xrT[(c0 + e) * 512 + b] = fmaxf(s[e] + e1b[c0 + e], 0.f);
}

// ---------------- K5: enc2 with relu(enc1)+skip concat -> out f32 [512][256]
// mode=1: xin is xrT [256][512], already biased+relu'd (coalesced reads)
// mode=0: xin is accum [512][256] raw sums (apply bias+relu here)
__global__ void __launch_bounds__(256) k5_enc2(
    const float* __restrict__ xin, const float* __restrict__ oT,
    const float* __restrict__ enc1b, const float* __restrict__ w2,
    const float* __restrict__ enc2b, float* __restrict__ outp, int mode) {
  int bg = blockIdx.x >> 3, og = blockIdx.x & 7;   // 64 blocks
  int lane = threadIdx.x & 63;
  int w = __builtin_amdgcn_readfirstlane((int)(threadIdx.x >> 6));
  int b = bg * 64 + lane;
  int obase = og * 32 + w * 8;
  float a8[8];
#pragma unroll
  for (int q = 0; q < 8; ++q) a8[q] = enc2b[obase + q];
  if (mode) {
    for (int c = 0; c < 256; ++c) {
      float x = xin[c * 512 + b];
#pragma unroll
      for (int q = 0; q < 8; ++q) a8[q] += w2[(obase + q) * 451 + c] * x;
    }
  } else {
    for (int c = 0; c < 256; ++c) {
      float x = fmaxf(xin[b * 256 + c] + enc1b[c], 0.f);
#pragma unroll
      for (int q = 0; q < 8; ++q) a8[q] += w2[(obase + q) * 451 + c] * x;
    }
  }
  for (int e = 0; e < 195; ++e) {
    float x = oT[e * 512 + b];   // rows: o1(65), o2(65), o3(65) — matches concat order
#pragma unroll
    for (int q = 0; q < 8; ++q) a8[q] += w2[(obase + q) * 451 + 256 + e] * x;
  }
#pragma unroll
  for (int q = 0; q < 8; ++q) outp[b * 256 + obase + q] = fmaxf(a8[q], 0.f);
}

extern "C" void kernel_launch(void* const* d_in, const int* in_sizes, int n_in,
                              void* d_out, int out_size, void* d_ws, size_t ws_size,
                              hipStream_t stream) {
  const float* vec1 = (const float*)d_in[0];
  const float* vec2 = (const float*)d_in[1];
  const float* vec3 = (const float*)d_in[2];
  const float* h1w = (const float*)d_in[3];  const float* h1b = (const float*)d_in[4];
  const float* z1w = (const float*)d_in[5];  const float* z1b = (const float*)d_in[6];
  const float* o1w = (const float*)d_in[7];  const float* o1b = (const float*)d_in[8];
  const float* h2w = (const float*)d_in[9];  const float* h2b = (const float*)d_in[10];
  const float* z2w = (const float*)d_in[11]; const float* z2b = (const float*)d_in[12];
  const float* o2w = (const float*)d_in[13]; const float* o2b = (const float*)d_in[14];
  const float* h3w = (const float*)d_in[15]; const float* h3b = (const float*)d_in[16];
  const float* z3w = (const float*)d_in[17]; const float* z3b = (const float*)d_in[18];
  const float* o3w = (const float*)d_in[19]; const float* o3b = (const float*)d_in[20];
  const float* e1w = (const float*)d_in[21]; const float* e1b = (const float*)d_in[22];
  const float* e2w = (const float*)d_in[23]; const float* e2b = (const float*)d_in[24];

  char* ws = (char*)d_ws;
  float* accum = (float*)(ws + 0);              // 512*256*4 = 524288 (mode1: xrT)
  float* oT    = (float*)(ws + 524288);         // 3*65*512*4 = 399360
  u16* o3row   = (u16*)  (ws + 923648);         // 512*72*2   = 73728
  float* xT    = (float*)(ws + 997376);         // 3*64*512*4 = 393216
  float* zsum  = (float*)(ws + 1390592);        // 3*64*512*4 = 393216
  float* pbuf  = (float*)(ws + 1783808);        // 64*512*256*4 = 33554432
  size_t need = 1783808 + (size_t)64 * 512 * 256 * 4;
  int mode = (ws_size >= need) ? 1 : 0;
  float* pArg = mode ? pbuf : accum;

  if (!mode) hipMemsetAsync(accum, 0, 524288, stream);

  hipLaunchKernelGGL(k0_transpose, dim3(384), dim3(256), 0, stream, vec1, vec2, vec3, xT);
  hipLaunchKernelGGL(k1_bilinear, dim3(384), dim3(256), 0, stream,
                     z1w, z2w, z3w, xT, zsum);
  hipLaunchKernelGGL(k2_branch, dim3(24), dim3(256), 0, stream,
                     h1w, h1b, o1w, o1b, h2w, h2b, o2w, o2b, h3w, h3b, o3w, o3b,
                     z1b, z2b, z3b, xT, zsum, oT, o3row);
  hipLaunchKernelGGL(k4_gemm, dim3(512), dim3(256), 0, stream, e1w, o3row, oT, accum,
                     pArg, mode);
  if (mode)
    hipLaunchKernelGGL(k4_reduce, dim3(128), dim3(256), 0, stream, pbuf, e1b, accum);
  hipLaunchKernelGGL(k5_enc2, dim3(64), dim3(256), 0, stream, accum, oT, e1b, e2w, e2b,
                     (float*)d_out, mode);
}

// Round 5
// 738.402 us; speedup vs baseline: 1.2224x; 1.0160x over previous
//
#include <hip/hip_runtime.h>
#include <hip/hip_bf16.h>
#include <stdint.h>

typedef unsigned short u16;
typedef unsigned int u32;

#define F1 274625   // 65^3
#define IJ1 4225    // 65^2

typedef float v4f __attribute__((ext_vector_type(4)));
typedef __bf16 v8bf __attribute__((ext_vector_type(8)));

__device__ __forceinline__ float lof(u32 u) { union { u32 u; float f; } c; c.u = u << 16; return c.f; }
__device__ __forceinline__ u16 f2bf(float f) {
  union { float f; u32 u; } c; c.f = f;
  u32 r = (c.u >> 16) & 1u;
  return (u16)((c.u + 0x7fffu + r) >> 16);
}
__device__ __forceinline__ u32 pkbf(u32 a, u32 b) {
  union { float f; u32 u; } ca, cb; ca.u = a; cb.u = b;
  __hip_bfloat162 h = __float22bfloat162_rn(make_float2(ca.f, cb.f));
  union { __hip_bfloat162 h; u32 u; } c; c.h = h; return c.u;
}

// ---------------- K0: transpose vec1/2/3 [512][64] f32 -> xT [3][64][512] f32
__global__ void __launch_bounds__(256) k0_transpose(const float* __restrict__ v1,
    const float* __restrict__ v2, const float* __restrict__ v3, float* __restrict__ xT) {
  int g = blockIdx.x * 256 + threadIdx.x;
  if (g >= 3 * 64 * 512) return;
  int t = g >> 15, r = g & 32767;
  int d = r >> 9, b = r & 511;
  const float* v = (t == 0) ? v1 : ((t == 1) ? v2 : v3);
  xT[g] = v[b * 64 + d];
}

// ---------------- K3T: w2 [256][451] -> w2T [451][256] (LDS-tiled)
__global__ void __launch_bounds__(256) k3t_w2t(const float* __restrict__ w2,
                                               float* __restrict__ w2T) {
  __shared__ float t[32][33];
  int bx = blockIdx.x & 7, by = blockIdx.x >> 3;   // 8 o-tiles x 15 c-tiles
  int tx = threadIdx.x & 31, ty = threadIdx.x >> 5; // ty 0..7
  int c = by * 32 + tx;
#pragma unroll
  for (int r = 0; r < 32; r += 8) {
    int o = bx * 32 + ty + r;
    t[ty + r][tx] = (c < 451) ? w2[o * 451 + c] : 0.f;
  }
  __syncthreads();
#pragma unroll
  for (int r = 0; r < 32; r += 8) {
    int cc = by * 32 + ty + r;
    if (cc < 451) w2T[cc * 256 + bx * 32 + tx] = t[tx][ty + r];
  }
}

// ---------------- K1: bilinear halves -> zsum [2][3][64][512] f32 (direct store)
// z_t[b,o] = sum_i x1[b,i] * sum_j zw_t[o,i,j] * vec3[b,j]; i split in 2 halves
__global__ void __launch_bounds__(256) k1_bilinear(
    const float* __restrict__ zw1, const float* __restrict__ zw2, const float* __restrict__ zw3,
    const float* __restrict__ xT, float* __restrict__ zsum) {
  int bid = blockIdx.x;                 // 768 = t*256 + o*4 + bh*2 + ih
  int ih = bid & 1, bh = (bid >> 1) & 1;
  int o = (bid >> 2) & 63, t = bid >> 8;
  int b = bh * 256 + threadIdx.x;
  const float* zw = (t == 0) ? zw1 : ((t == 1) ? zw2 : zw3);
  const float* xiT = xT + ((t == 1) ? 32768 : 0);  // branches 0,2 use vec1; 1 uses vec2
  const float* x3T = xT + 65536;                   // j-side is always vec3
  float x3r[64];
#pragma unroll
  for (int j = 0; j < 64; ++j) x3r[j] = x3T[j * 512 + b];   // coalesced
  const float4* w4 = (const float4*)(zw + o * 4096);
  float acc = 0.f;
  int i0 = ih * 32;
#pragma unroll 4
  for (int i = i0; i < i0 + 32; ++i) {
    float xi = xiT[i * 512 + b];                             // coalesced
    float s = 0.f;
#pragma unroll
    for (int q = 0; q < 16; ++q) {
      float4 w = w4[i * 16 + q];   // uniform index -> scalar loads
      s += w.x * x3r[q*4+0] + w.y * x3r[q*4+1] + w.z * x3r[q*4+2] + w.w * x3r[q*4+3];
    }
    acc += xi * s;
  }
  zsum[ih * 98304 + t * 32768 + o * 512 + b] = acc;
}

// ---------------- K2: per-branch h/o layers -> oT f32 [3][65][512], o3row bf16 [512][72]
__global__ void __launch_bounds__(256) k2_branch(
    const float* __restrict__ hw1, const float* __restrict__ hb1,
    const float* __restrict__ ow1, const float* __restrict__ ob1,
    const float* __restrict__ hw2, const float* __restrict__ hb2,
    const float* __restrict__ ow2, const float* __restrict__ ob2,
    const float* __restrict__ hw3, const float* __restrict__ hb3,
    const float* __restrict__ ow3, const float* __restrict__ ob3,
    const float* __restrict__ zb1, const float* __restrict__ zb2, const float* __restrict__ zb3,
    const float* __restrict__ xT, const float* __restrict__ zsum,
    float* __restrict__ oT, u16* __restrict__ o3row) {
  int t = blockIdx.x >> 3, bc = blockIdx.x & 7;   // 24 blocks
  int lane = threadIdx.x & 63;
  int w = __builtin_amdgcn_readfirstlane((int)(threadIdx.x >> 6));
  int b = bc * 64 + lane;
  const float* hw = (t==0)?hw1:((t==1)?hw2:hw3);
  const float* hb = (t==0)?hb1:((t==1)?hb2:hb3);
  const float* ow = (t==0)?ow1:((t==1)?ow2:ow3);
  const float* ob = (t==0)?ob1:((t==1)?ob2:ob3);
  const float* zb = (t==0)?zb1:((t==1)?zb2:zb3);
  const float* xtT = xT + t * 32768;
  const float4* hw4 = (const float4*)hw;
  const float4* ow4 = (const float4*)ow;
  __shared__ float gT[64][68];
  float xr[64];
#pragma unroll
  for (int k = 0; k < 64; ++k) xr[k] = xtT[k * 512 + b];     // coalesced
#pragma unroll
  for (int ii = 0; ii < 16; ii += 4) {
    float gv[4];
#pragma unroll
    for (int q = 0; q < 4; ++q) {
      int i = w * 16 + ii + q;
      float a = hb[i];
#pragma unroll
      for (int kq = 0; kq < 16; ++kq) {
        float4 h4 = hw4[i * 16 + kq];
        a += h4.x * xr[kq*4+0] + h4.y * xr[kq*4+1] + h4.z * xr[kq*4+2] + h4.w * xr[kq*4+3];
      }
      float hv = fmaxf(a, 0.f);
      int zi = t * 32768 + i * 512 + b;
      float z = zsum[zi] + zsum[98304 + zi] + zb[i];
      float sg = 1.f / (1.f + __expf(-z));
      gv[q] = sg * hv;
    }
    *(float4*)&gT[lane][w * 16 + ii] = make_float4(gv[0], gv[1], gv[2], gv[3]);
  }
  __syncthreads();
  float gr[64];
#pragma unroll
  for (int k = 0; k < 64; k += 4) {
    float4 g4 = *(const float4*)&gT[lane][k];
    gr[k] = g4.x; gr[k+1] = g4.y; gr[k+2] = g4.z; gr[k+3] = g4.w;
  }
#pragma unroll
  for (int ii = 0; ii < 16; ++ii) {
    int oo = w * 16 + ii;
    float a = ob[oo];
#pragma unroll
    for (int kq = 0; kq < 16; ++kq) {
      float4 o4 = ow4[oo * 16 + kq];
      a += o4.x * gr[kq*4+0] + o4.y * gr[kq*4+1] + o4.z * gr[kq*4+2] + o4.w * gr[kq*4+3];
    }
    float ov = fmaxf(a, 0.f);
    oT[(t * 65 + oo) * 512 + b] = ov;
    if (t == 2) o3row[b * 72 + oo] = f2bf(ov);
  }
  if (w == 0) oT[(t * 65 + 64) * 512 + b] = 1.f;       // ones column
  if (t == 2 && w == 1) {
    uint4 ones = make_uint4(0x3F80u, 0u, 0u, 0u);      // bf16 1.0, then zero pad
    *(uint4*)&o3row[b * 72 + 64] = ones;
  }
}

// pack one staged W row-half into 8-chunk-permuted LDS row (stride 64 u16 = 128B).
// Permutation: logical 16B chunk lc lands at slot (lc + (row>>2) + 2*(row&3)) & 7
// -> staging stores span 8 slots (32 banks); fragment reads are 2-way (free).
template<int S4>
__device__ __forceinline__ void pack_row(const uint4* qv, u16* bp, u16* vvp,
                                         int row, int hh) {
  u32 l[36];
#pragma unroll
  for (int r = 0; r < 9; ++r) {
    l[4*r+0] = qv[r].x; l[4*r+1] = qv[r].y; l[4*r+2] = qv[r].z; l[4*r+3] = qv[r].w;
  }
  int rp = (row >> 2) + 2 * (row & 3);
#pragma unroll
  for (int cl = 0; cl < 4; ++cl) {
    u32 p0 = pkbf(l[S4+8*cl+0], l[S4+8*cl+1]);
    u32 p1 = pkbf(l[S4+8*cl+2], l[S4+8*cl+3]);
    u32 p2 = pkbf(l[S4+8*cl+4], l[S4+8*cl+5]);
    u32 p3 = pkbf(l[S4+8*cl+6], l[S4+8*cl+7]);
    int pos = (hh * 4 + cl + rp) & 7;
    *(uint4*)(bp + (pos << 3)) = make_uint4(p0, p1, p2, p3);
  }
  if (hh) vvp[row] = (u16)(pkbf(l[S4+32], l[S4+32]) & 0xffffu);  // col 64
}

// ---------------- K4: main GEMM: C[b,o] = sum_f o123[b,f]*W1[o,f]
// 128x128 tile, depth-2 register prefetch (qa/qb), compact permuted LDS,
// dbuf Bs + single lgkm barrier per ij (global prefetch in flight across it).
__global__ void __launch_bounds__(256, 2) k4_gemm(
    const float* __restrict__ W, const u16* __restrict__ o3row,
    const float* __restrict__ oT, float* __restrict__ accum,
    float* __restrict__ pbuf, int mode) {
  __shared__ u16 o3r[128 * 64];        // permuted, stride 128B, 16 KB
  __shared__ u16 Bs[2][128 * 64];      // permuted, 2x16 KB
  __shared__ u16 vvs[2][128];          // col-64 of each staged row
  __shared__ float o12sf[2][128];
  int bid = blockIdx.x;                // 512; 4 mb-sharers of a W slice on same XCD
  int xcd = bid & 7, slot = bid >> 3;
  int mb = slot & 3, ph = slot >> 2;   // ph 0..15
  int pair = ph * 8 + xcd;             // 0..127
  int sK = pair >> 1, nb = pair & 1;   // 64 split-K segments
  int mbase = mb * 128, nbase = nb * 128;
  int ij0 = (sK * IJ1) >> 6, ij1 = ((sK + 1) * IJ1) >> 6;
  int tid = threadIdx.x;
  int lane = tid & 63;
  int wid = __builtin_amdgcn_readfirstlane(tid >> 6);
  int wm = wid >> 1, wn = wid & 1;
  int lrow = lane & 15, lkg = lane >> 4;
  int rpos = lane >> 1, hh = lane & 1;   // 32 row-slots per wave, 2 threads/row

  v4f acc[16] = {};
  const uint4* Wq = (const uint4*)W;
  uint4 qa[9], qb[9];
  float aA = 0.f, aB = 0.f, bA = 0.f, bB = 0.f;

  auto loadW = [&](int ij, uint4* q) {
    int cc = (wid - ij) & 3;             // row rotation -> wave-uniform align phase
    int row = rpos * 4 + cc;
    long g = (long)(nbase + row) * F1 + (long)ij * 65;
    long u4 = (g >> 2) + (long)hh * 8;
#pragma unroll
    for (int r = 0; r < 9; ++r) q[r] = Wq[u4 + r];
  };
  auto loadO = [&](int ij, float& A, float& B) {
    if (tid < 128) {
      int i = ij / 65, j = ij - i * 65;
      A = oT[i * 512 + mbase + tid];
      B = oT[(65 + j) * 512 + mbase + tid];
    }
  };
  auto packCur = [&](int ij, int buf, const uint4* q, float pA, float pB) {
    int cc = (wid - ij) & 3;
    int row = rpos * 4 + cc;
    u16* bp = &Bs[buf][row << 6];
    if      (wid == 0) pack_row<0>(q, bp, &vvs[buf][0], row, hh);
    else if (wid == 1) pack_row<1>(q, bp, &vvs[buf][0], row, hh);
    else if (wid == 2) pack_row<2>(q, bp, &vvs[buf][0], row, hh);
    else               pack_row<3>(q, bp, &vvs[buf][0], row, hh);
    if (tid < 128) o12sf[buf][tid] = pA * pB;
  };

  loadW(ij0, qa); loadO(ij0, aA, aB);

  // persistent o3 rows [128][64 cols] -> permuted layout
  for (int u = tid; u < 1024; u += 256) {
    int r = u >> 3, c = u & 7;
    uint4 v = *(const uint4*)(o3row + (mbase + r) * 72 + c * 8);
    int pos = (c + (r >> 2) + 2 * (r & 3)) & 7;
    *(uint4*)&o3r[(r << 6) + (pos << 3)] = v;
  }

  loadW(ij0 + 1, qb); loadO(ij0 + 1, bA, bB);

  // fragment u16-offsets (logical chunk lc = k2*4 + lkg)
  int aoff[4][2], boff[4][2], vvr[4];
#pragma unroll
  for (int u = 0; u < 4; ++u) {
    int ra = wm * 64 + u * 16 + lrow;
    int rb = wn * 64 + u * 16 + lrow;
#pragma unroll
    for (int k2 = 0; k2 < 2; ++k2) {
      aoff[u][k2] = (ra << 6) + (((k2 * 4 + lkg + (ra >> 2) + 2 * (ra & 3)) & 7) << 3);
      boff[u][k2] = (rb << 6) + (((k2 * 4 + lkg + (rb >> 2) + 2 * (rb & 3)) & 7) << 3);
    }
    vvr[u] = rb;
  }

  __syncthreads();                       // o3r ready
  packCur(ij0, 0, qa, aA, aB);
  loadW(ij0 + 2, qa); loadO(ij0 + 2, aA, aB);
  asm volatile("s_waitcnt lgkmcnt(0)\n\ts_barrier" ::: "memory");

#pragma unroll 1
  for (int ij = ij0; ij < ij1; ++ij) {
    int cur = (ij - ij0) & 1;
    if (ij + 1 < ij1) {
      if (cur == 0) {
        packCur(ij + 1, 1, qb, bA, bB);
        if (ij + 3 < ij1) { loadW(ij + 3, qb); loadO(ij + 3, bA, bB); }
      } else {
        packCur(ij + 1, 0, qa, aA, aB);
        if (ij + 3 < ij1) { loadW(ij + 3, qa); loadO(ij + 3, aA, aB); }
      }
    }
    const u16* bs = Bs[cur];
    v8bf bfr[4][2];
#pragma unroll
    for (int u2 = 0; u2 < 4; ++u2)
#pragma unroll
      for (int k2 = 0; k2 < 2; ++k2)
        bfr[u2][k2] = *(const v8bf*)&bs[boff[u2][k2]];
    float vv[4];
#pragma unroll
    for (int u2 = 0; u2 < 4; ++u2) vv[u2] = lof((u32)vvs[cur][vvr[u2]]);
    __builtin_amdgcn_s_setprio(1);
#pragma unroll
    for (int t2 = 0; t2 < 4; ++t2) {
      v8bf a0 = *(const v8bf*)&o3r[aoff[t2][0]];
      v8bf a1 = *(const v8bf*)&o3r[aoff[t2][1]];
      v4f P0 = {}, P1 = {}, P2 = {}, P3 = {};
      P0 = __builtin_amdgcn_mfma_f32_16x16x32_bf16(a0, bfr[0][0], P0, 0, 0, 0);
      P0 = __builtin_amdgcn_mfma_f32_16x16x32_bf16(a1, bfr[0][1], P0, 0, 0, 0);
      P1 = __builtin_amdgcn_mfma_f32_16x16x32_bf16(a0, bfr[1][0], P1, 0, 0, 0);
      P1 = __builtin_amdgcn_mfma_f32_16x16x32_bf16(a1, bfr[1][1], P1, 0, 0, 0);
      P2 = __builtin_amdgcn_mfma_f32_16x16x32_bf16(a0, bfr[2][0], P2, 0, 0, 0);
      P2 = __builtin_amdgcn_mfma_f32_16x16x32_bf16(a1, bfr[2][1], P2, 0, 0, 0);
      P3 = __builtin_amdgcn_mfma_f32_16x16x32_bf16(a0, bfr[3][0], P3, 0, 0, 0);
      P3 = __builtin_amdgcn_mfma_f32_16x16x32_bf16(a1, bfr[3][1], P3, 0, 0, 0);
      float4 sp = *(const float4*)&o12sf[cur][wm * 64 + t2 * 16 + lkg * 4];
#pragma unroll
      for (int e = 0; e < 4; ++e) {
        float se = (e == 0) ? sp.x : (e == 1) ? sp.y : (e == 2) ? sp.z : sp.w;
        acc[t2 * 4 + 0][e] += se * (P0[e] + vv[0]);
        acc[t2 * 4 + 1][e] += se * (P1[e] + vv[1]);
        acc[t2 * 4 + 2][e] += se * (P2[e] + vv[2]);
        acc[t2 * 4 + 3][e] += se * (P3[e] + vv[3]);
      }
    }
    __builtin_amdgcn_s_setprio(0);
    asm volatile("s_waitcnt lgkmcnt(0)\n\ts_barrier" ::: "memory");
  }

  if (mode) {
    float* dst = pbuf + ((long)sK << 17);
#pragma unroll
    for (int t2 = 0; t2 < 4; ++t2) {
      int gb0 = mbase + wm * 64 + t2 * 16 + lkg * 4;
#pragma unroll
      for (int u2 = 0; u2 < 4; ++u2) {
        int go = nbase + wn * 64 + u2 * 16 + lrow;
#pragma unroll
        for (int e = 0; e < 4; ++e)
          dst[(gb0 + e) * 256 + go] = acc[t2 * 4 + u2][e];
      }
    }
  } else {
#pragma unroll
    for (int t2 = 0; t2 < 4; ++t2) {
      int gb0 = mbase + wm * 64 + t2 * 16 + lkg * 4;
#pragma unroll
      for (int u2 = 0; u2 < 4; ++u2) {
        int go = nbase + wn * 64 + u2 * 16 + lrow;
#pragma unroll
        for (int e = 0; e < 4; ++e)
          atomicAdd(&accum[(gb0 + e) * 256 + go], acc[t2 * 4 + u2][e]);
      }
    }
  }
}

// ---------------- K4R: reduce split-K partials, add enc1 bias, relu, TRANSPOSE
// pbuf [64][512][256] -> xrT [256][512]  (written into the accum slot; mode=1 only)
__global__ void __launch_bounds__(256) k4_reduce(const float* __restrict__ P,
    const float* __restrict__ e1b, float* __restrict__ xrT) {
  int g = blockIdx.x * 256 + threadIdx.x;       // float4 index, 32768 total
  const v4f* p4 = (const v4f*)P;
  v4f s = p4[g];
#pragma unroll 4
  for (int k = 1; k < 64; ++k) s += p4[(k << 15) + g];
  int b = g >> 6, c0 = (g & 63) << 2;
#pragma unroll
  for (int e = 0; e < 4; ++e)
    xrT[(c0 + e) * 512 + b] = fmaxf(s[e] + e1b[c0 + e], 0.f);
}

// ---------------- K5V (mode=1): enc2 via transposed weights, vector loads.
// lanes = output col; x tile [451][8] staged in LDS; w2T reads coalesced.
__global__ void __launch_bounds__(256) k5v_enc2(const float* __restrict__ xrT,
    const float* __restrict__ oT, const float* __restrict__ w2T,
    const float* __restrict__ enc2b, float* __restrict__ outp) {
  __shared__ float xl[451 * 8 + 8];
  int b0 = blockIdx.x * 8;                      // 64 blocks
  int tid = threadIdx.x;
  for (int u = tid; u < 3608; u += 256) {
    int c = u >> 3, bi = u & 7;
    xl[u] = (c < 256) ? xrT[c * 512 + b0 + bi] : oT[(c - 256) * 512 + b0 + bi];
  }
  float a[8];
  float bv = enc2b[tid];
#pragma unroll
  for (int q = 0; q < 8; ++q) a[q] = bv;
  __syncthreads();
#pragma unroll 4
  for (int c = 0; c < 451; ++c) {
    float w = w2T[c * 256 + tid];               // coalesced vector load
    float4 x0 = *(const float4*)&xl[c * 8];     // LDS broadcast
    float4 x1 = *(const float4*)&xl[c * 8 + 4];
    a[0] += w * x0.x; a[1] += w * x0.y; a[2] += w * x0.z; a[3] += w * x0.w;
    a[4] += w * x1.x; a[5] += w * x1.y; a[6] += w * x1.z; a[7] += w * x1.w;
  }
#pragma unroll
  for (int q = 0; q < 8; ++q) outp[(b0 + q) * 256 + tid] = fmaxf(a[q], 0.f);
}

// ---------------- K5 (mode=0 fallback): old scalar path
__global__ void __launch_bounds__(256) k5_enc2(
    const float* __restrict__ xin, const float* __restrict__ oT,
    const float* __restrict__ enc1b, const float* __restrict__ w2,
    const float* __restrict__ enc2b, float* __restrict__ outp) {
  int bg = blockIdx.x >> 3, og = blockIdx.x & 7;   // 64 blocks
  int lane = threadIdx.x & 63;
  int w = __builtin_amdgcn_readfirstlane((int)(threadIdx.x >> 6));
  int b = bg * 64 + lane;
  int obase = og * 32 + w * 8;
  float a8[8];
#pragma unroll
  for (int q = 0; q < 8; ++q) a8[q] = enc2b[obase + q];
  for (int c = 0; c < 256; ++c) {
    float x = fmaxf(xin[b * 256 + c] + enc1b[c], 0.f);
#pragma unroll
    for (int q = 0; q < 8; ++q) a8[q] += w2[(obase + q) * 451 + c] * x;
  }
  for (int e = 0; e < 195; ++e) {
    float x = oT[e * 512 + b];
#pragma unroll
    for (int q = 0; q < 8; ++q) a8[q] += w2[(obase + q) * 451 + 256 + e] * x;
  }
#pragma unroll
  for (int q = 0; q < 8; ++q) outp[b * 256 + obase + q] = fmaxf(a8[q], 0.f);
}

extern "C" void kernel_launch(void* const* d_in, const int* in_sizes, int n_in,
                              void* d_out, int out_size, void* d_ws, size_t ws_size,
                              hipStream_t stream) {
  const float* vec1 = (const float*)d_in[0];
  const float* vec2 = (const float*)d_in[1];
  const float* vec3 = (const float*)d_in[2];
  const float* h1w = (const float*)d_in[3];  const float* h1b = (const float*)d_in[4];
  const float* z1w = (const float*)d_in[5];  const float* z1b = (const float*)d_in[6];
  const float* o1w = (const float*)d_in[7];  const float* o1b = (const float*)d_in[8];
  const float* h2w = (const float*)d_in[9];  const float* h2b = (const float*)d_in[10];
  const float* z2w = (const float*)d_in[11]; const float* z2b = (const float*)d_in[12];
  const float* o2w = (const float*)d_in[13]; const float* o2b = (const float*)d_in[14];
  const float* h3w = (const float*)d_in[15]; const float* h3b = (const float*)d_in[16];
  const float* z3w = (const float*)d_in[17]; const float* z3b = (const float*)d_in[18];
  const float* o3w = (const float*)d_in[19]; const float* o3b = (const float*)d_in[20];
  const float* e1w = (const float*)d_in[21]; const float* e1b = (const float*)d_in[22];
  const float* e2w = (const float*)d_in[23]; const float* e2b = (const float*)d_in[24];

  char* ws = (char*)d_ws;
  float* accum = (float*)(ws + 0);              // 524288 (mode1: xrT [256][512])
  float* oT    = (float*)(ws + 524288);         // 3*65*512*4 = 399360
  u16* o3row   = (u16*)  (ws + 923648);         // 512*72*2   = 73728
  float* xT    = (float*)(ws + 997376);         // 3*64*512*4 = 393216
  float* zsum  = (float*)(ws + 1390592);        // 2*3*64*512*4 = 786432
  float* w2T   = (float*)(ws + 2177024);        // 451*256*4 = 461824
  float* pbuf  = (float*)(ws + 2638848);        // 64*512*256*4 = 33554432
  size_t need = 2638848 + (size_t)64 * 512 * 256 * 4;   // 36193280
  int mode = (ws_size >= need) ? 1 : 0;
  float* pArg = mode ? pbuf : accum;

  if (!mode) hipMemsetAsync(accum, 0, 524288, stream);

  hipLaunchKernelGGL(k0_transpose, dim3(384), dim3(256), 0, stream, vec1, vec2, vec3, xT);
  if (mode)
    hipLaunchKernelGGL(k3t_w2t, dim3(120), dim3(256), 0, stream, e2w, w2T);
  hipLaunchKernelGGL(k1_bilinear, dim3(768), dim3(256), 0, stream,
                     z1w, z2w, z3w, xT, zsum);
  hipLaunchKernelGGL(k2_branch, dim3(24), dim3(256), 0, stream,
                     h1w, h1b, o1w, o1b, h2w, h2b, o2w, o2b, h3w, h3b, o3w, o3b,
                     z1b, z2b, z3b, xT, zsum, oT, o3row);
  hipLaunchKernelGGL(k4_gemm, dim3(512), dim3(256), 0, stream, e1w, o3row, oT, accum,
                     pArg, mode);
  if (mode) {
    hipLaunchKernelGGL(k4_reduce, dim3(128), dim3(256), 0, stream, pbuf, e1b, accum);
    hipLaunchKernelGGL(k5v_enc2, dim3(64), dim3(256), 0, stream, accum, oT, w2T, e2b,
                       (float*)d_out);
  } else {
    hipLaunchKernelGGL(k5_enc2, dim3(64), dim3(256), 0, stream, accum, oT, e1b, e2w, e2b,
                       (float*)d_out);
  }
}